// Round 13
// baseline (339.527 us; speedup 1.0000x reference)
//
#include <hip/hip_runtime.h>

// Problem constants (B=64, T=4096, D=100, K=4, BETA=0.25)
#define D_DIM   100
#define K_CODES 4
#define RPB     64      // rows per gemm tile
#define TPB     256
#define PITCH   65      // f32 h^T-tile pitch (words), gemm writeout
#define N_ROWS  262144  // B*T
#define KP      128
#define NP      128
#define TAU     2.0f    // f32 d2 margin -> exact recompute (safer than all passing rounds)
#define GRID_GEMM 1024  // gemm blocks x 4 tiles
#define NTILES  4

typedef __attribute__((ext_vector_type(8))) __bf16 bf16x8;
typedef __attribute__((ext_vector_type(4))) float  f32x4;

__device__ __forceinline__ unsigned short f2bf_rne(float f) {
    unsigned int u = __builtin_bit_cast(unsigned int, f);
    unsigned int r = u + 0x7fffu + ((u >> 16) & 1u);
    return (unsigned short)(r >> 16);
}
__device__ __forceinline__ float bf2f(unsigned short b) {
    unsigned int u = ((unsigned int)b) << 16;
    return __builtin_bit_cast(float, u);
}
__device__ __forceinline__ void load_lds16(const float* g, float* s) {
    __builtin_amdgcn_global_load_lds(
        (const __attribute__((address_space(1))) unsigned int*)g,
        (__attribute__((address_space(3))) unsigned int*)s, 16, 0, 0);
}
__device__ __forceinline__ void stage_x(const float* xg, float* s, int wave, int lane) {
    #pragma unroll
    for (int it = 0; it < 6; ++it) {
        int cbase = it * 256 + wave * 64;
        load_lds16(xg + (size_t)(cbase + lane) * 4, s + cbase * 4);
    }
    if (wave == 0) load_lds16(xg + (size_t)(1536 + lane) * 4, s + 1536 * 4);
}

// R6-proven exact recompute (R1 arithmetic); wave-cooperative; result in all lanes.
__device__ __forceinline__ int exact_row_argmin(
    const float* __restrict__ x, const float* __restrict__ W1,
    const float* __restrict__ b1, const float* __restrict__ cb,
    int gr, int lane)
{
    const int e1 = lane;
    const int e2 = 64 + lane;
    const bool has2 = (e2 < D_DIM);
    float z1 = b1[e1];
    float z2 = has2 ? b1[e2] : 0.0f;
    const float* xr  = x + (size_t)gr * D_DIM;
    const float* w1r = W1 + e1 * D_DIM;
    const float* w2r = W1 + (has2 ? e2 : 0) * D_DIM;
    #pragma unroll
    for (int d4 = 0; d4 < 25; ++d4) {
        float4 xv = reinterpret_cast<const float4*>(xr)[d4];
        float4 wa = reinterpret_cast<const float4*>(w1r)[d4];
        z1 = fmaf(xv.x, wa.x, z1); z1 = fmaf(xv.y, wa.y, z1);
        z1 = fmaf(xv.z, wa.z, z1); z1 = fmaf(xv.w, wa.w, z1);
        float4 wb = reinterpret_cast<const float4*>(w2r)[d4];
        z2 = fmaf(xv.x, wb.x, z2); z2 = fmaf(xv.y, wb.y, z2);
        z2 = fmaf(xv.z, wb.z, z2); z2 = fmaf(xv.w, wb.w, z2);
    }
    float h1 = fmaxf(z1, 0.0f);
    float h2 = fmaxf(z2, 0.0f);
    double dk[K_CODES];
    #pragma unroll
    for (int k = 0; k < K_CODES; ++k) {
        double p;
        {
            double dh = (double)h1 - (double)cb[k * D_DIM + e1];
            p = dh * dh;
        }
        if (has2) {
            double dh = (double)h2 - (double)cb[k * D_DIM + e2];
            p = fma(dh, dh, p);
        }
        for (int off = 32; off > 0; off >>= 1)
            p += __shfl_down(p, off);
        dk[k] = p;
    }
    int bi_ex = 0;
    double best = dk[0];
    #pragma unroll
    for (int k = 1; k < K_CODES; ++k)
        if (dk[k] < best) { best = dk[k]; bi_ex = k; }
    return __shfl(bi_ex, 0);
}

// ---------------- pre-kernel: split W1 into padded bf16 hi/lo [NP][KP] ----------------
__global__ __launch_bounds__(256) void split_w_kernel(
    const float* __restrict__ W1,
    unsigned short* __restrict__ Whi, unsigned short* __restrict__ Wlo)
{
    int i = blockIdx.x * 256 + threadIdx.x;
    if (i >= NP * KP) return;
    int n = i / KP, k = i % KP;
    float w = (n < D_DIM && k < D_DIM) ? W1[n * D_DIM + k] : 0.0f;
    unsigned short hb = f2bf_rne(w);
    float lo = w - bf2f(hb);
    Whi[i] = hb;
    Wlo[i] = f2bf_rne(lo);
}

// ---------------- Kernel A: R9 gemm v3 verbatim (clean float4 writes) ----------------
__global__ __launch_bounds__(TPB, 4) void gemm_relu_mfma(
    const float* __restrict__ x,
    const unsigned short* __restrict__ Whi, const unsigned short* __restrict__ Wlo,
    const float* __restrict__ b1, float* __restrict__ out_h)
{
    __shared__ __align__(16) float buf0[6500];
    __shared__ __align__(16) float buf1[6500];
    const int tid  = threadIdx.x;
    const int lane = tid & 63;
    const int wave = tid >> 6;

    const int bcol0 = wave * 32;
    const int bn  = lane & 15;
    const int bk  = (lane >> 4) * 8;
    bf16x8 bh[2][4], bl[2][4];
    #pragma unroll
    for (int ct = 0; ct < 2; ++ct) {
        int n = bcol0 + ct * 16 + bn;
        #pragma unroll
        for (int kt = 0; kt < 4; ++kt) {
            int off = n * KP + kt * 32 + bk;
            bh[ct][kt] = *reinterpret_cast<const bf16x8*>(Whi + off);
            bl[ct][kt] = *reinterpret_cast<const bf16x8*>(Wlo + off);
        }
    }
    float bias[2];
    #pragma unroll
    for (int ct = 0; ct < 2; ++ct) {
        int n = bcol0 + ct * 16 + bn;
        bias[ct] = (n < D_DIM) ? b1[n] : 0.0f;
    }
    if (tid < 32) { buf0[6400 + tid] = 0.0f; buf1[6400 + tid] = 0.0f; }
    stage_x(x + (size_t)blockIdx.x * RPB * D_DIM, buf0, wave, lane);

    const int am = lane & 15;
    const int ak = (lane >> 4) * 8;

    for (int it = 0; it < NTILES; ++it) {
        const int tile = blockIdx.x + it * GRID_GEMM;
        const int rowBase = tile * RPB;
        float* cur = (it & 1) ? buf1 : buf0;
        float* nxt = (it & 1) ? buf0 : buf1;

        __syncthreads();
        if (it + 1 < NTILES)
            stage_x(x + (size_t)(blockIdx.x + (it + 1) * GRID_GEMM) * RPB * D_DIM,
                    nxt, wave, lane);

        f32x4 acc[4][2];
        #pragma unroll
        for (int rt = 0; rt < 4; ++rt) {
            acc[rt][0] = (f32x4){0.f, 0.f, 0.f, 0.f};
            acc[rt][1] = (f32x4){0.f, 0.f, 0.f, 0.f};
        }
        #pragma unroll
        for (int rt = 0; rt < 4; ++rt) {
            const int rbase = (rt * 16 + am) * D_DIM;
            #pragma unroll
            for (int kt = 0; kt < 4; ++kt) {
                const float* p = cur + rbase + kt * 32 + ak;
                f32x4 f0 = *reinterpret_cast<const f32x4*>(p);
                f32x4 f1 = *reinterpret_cast<const f32x4*>(p + 4);
                bf16x8 ah, al;
                #pragma unroll
                for (int i = 0; i < 4; ++i) {
                    __bf16 h0 = (__bf16)f0[i];
                    ah[i] = h0;
                    al[i] = (__bf16)(f0[i] - (float)h0);
                    __bf16 h1 = (__bf16)f1[i];
                    ah[4 + i] = h1;
                    al[4 + i] = (__bf16)(f1[i] - (float)h1);
                }
                acc[rt][0] = __builtin_amdgcn_mfma_f32_16x16x32_bf16(ah, bl[0][kt], acc[rt][0], 0, 0, 0);
                acc[rt][0] = __builtin_amdgcn_mfma_f32_16x16x32_bf16(al, bh[0][kt], acc[rt][0], 0, 0, 0);
                acc[rt][0] = __builtin_amdgcn_mfma_f32_16x16x32_bf16(ah, bh[0][kt], acc[rt][0], 0, 0, 0);
                acc[rt][1] = __builtin_amdgcn_mfma_f32_16x16x32_bf16(ah, bl[1][kt], acc[rt][1], 0, 0, 0);
                acc[rt][1] = __builtin_amdgcn_mfma_f32_16x16x32_bf16(al, bh[1][kt], acc[rt][1], 0, 0, 0);
                acc[rt][1] = __builtin_amdgcn_mfma_f32_16x16x32_bf16(ah, bh[1][kt], acc[rt][1], 0, 0, 0);
            }
        }
        __syncthreads();

        #pragma unroll
        for (int rt = 0; rt < 4; ++rt) {
            int rb = rt * 16 + (lane >> 4) * 4;
            #pragma unroll
            for (int ct = 0; ct < 2; ++ct) {
                int n = bcol0 + ct * 16 + bn;
                if (n < D_DIM) {
                    #pragma unroll
                    for (int i = 0; i < 4; ++i)
                        cur[n * PITCH + rb + i] = fmaxf(acc[rt][ct][i] + bias[ct], 0.0f);
                }
            }
        }
        __syncthreads();

        float* hg = out_h + (size_t)rowBase * D_DIM;
        for (int v = tid; v < RPB * 25; v += TPB) {
            int r = v / 25;
            int d = (v % 25) * 4;
            reinterpret_cast<float4*>(hg)[v] = make_float4(
                cur[d * PITCH + r], cur[(d + 1) * PITCH + r],
                cur[(d + 2) * PITCH + r], cur[(d + 3) * PITCH + r]);
        }
    }
}

// ---------------- Kernel B (v3): LDS-free, barrier-free per-wave VQ ----------------
// lane = row. f32 d2 in-register (cb via uniform s_load), margin-guarded exact
// recompute (R6-proven), coalesced payload/aux, f64 loss partial per wave.
__global__ __launch_bounds__(TPB, 4) void vq_kernel(
    const float* __restrict__ h, const float* __restrict__ x,
    const float* __restrict__ W1, const float* __restrict__ b1,
    const float* __restrict__ cb, const int* __restrict__ qflag,
    float* __restrict__ out_pay, float* __restrict__ out_aux,
    double* __restrict__ partials)
{
    const int lane = threadIdx.x & 63;
    const int wave = threadIdx.x >> 6;
    const int wg   = blockIdx.x * 4 + wave;     // 1024 blocks x 4 waves = 4096
    const int rowBase = wg * 64;
    const int qz = *qflag;

    if (qz) {
        // ---- f32 d2 for own row, all 4 codes; cb chunks are lane-uniform (s_load) ----
        const float* hr = h + (size_t)(rowBase + lane) * D_DIM;   // 16B-aligned (400B rows)
        float s[K_CODES] = {0.f, 0.f, 0.f, 0.f};
        #pragma unroll
        for (int c = 0; c < 25; ++c) {
            f32x4 hv = *reinterpret_cast<const f32x4*>(hr + c * 4);
            #pragma unroll
            for (int k = 0; k < K_CODES; ++k) {
                f32x4 cv = *reinterpret_cast<const f32x4*>(cb + k * D_DIM + c * 4);
                #pragma unroll
                for (int i = 0; i < 4; ++i) {
                    float e = hv[i] - cv[i];
                    s[k] = fmaf(e, e, s[k]);
                }
            }
        }
        // ---- per-lane argmin (first-min) + margin flag ----
        float best = s[0], second = 3.4e38f;
        int bi = 0;
        #pragma unroll
        for (int k = 1; k < K_CODES; ++k) {
            float v = s[k];
            if (v < best) { second = best; best = v; bi = k; }
            else if (v < second) { second = v; }
        }
        const bool flg = (second - best) < TAU;

        // ---- flagged rows: wave-cooperative exact recompute (rare) ----
        unsigned long long m = __ballot(flg);
        while (m) {
            int r = __ffsll((long long)m) - 1;
            m &= m - 1;
            int bx = exact_row_argmin(x, W1, b1, cb, rowBase + r, lane);
            if (lane == r) bi = bx;
        }

        // ---- payload (256B contiguous per wave) ----
        out_pay[rowBase + lane] = (float)bi;

        // ---- loss partial: f64 accumulate of f32 d2min (R12-proven formulation) ----
        double la = (double)s[bi];
        for (int off = 32; off > 0; off >>= 1)
            la += __shfl_down(la, off);
        if (lane == 0) partials[wg] = la;

        // ---- aux writeout: perfectly contiguous float4 per wave ----
        float* ag = out_aux + (size_t)rowBase * D_DIM;
        #pragma unroll
        for (int it = 0; it < 25; ++it) {
            int v = it * 64 + lane;
            int r = v / 25;
            int d = (v % 25) * 4;
            int bir = __shfl(bi, r);
            reinterpret_cast<float4*>(ag)[v] =
                *reinterpret_cast<const float4*>(cb + bir * D_DIM + d);
        }
    } else {
        out_pay[rowBase + lane] = 0.0f;
        if (lane == 0) partials[wg] = 0.0;
        float* ag = out_aux + (size_t)rowBase * D_DIM;
        #pragma unroll
        for (int it = 0; it < 25; ++it)
            reinterpret_cast<float4*>(ag)[it * 64 + lane] = make_float4(0, 0, 0, 0);
    }
}

// ---------------- deterministic final loss reduce ----------------
__global__ __launch_bounds__(256) void vq_final_kernel(
    const double* __restrict__ partials, int n, float* __restrict__ loss_out)
{
    __shared__ double sm[256];
    int tid = threadIdx.x;
    double s = 0.0;
    for (int i = tid; i < n; i += 256) s += partials[i];
    sm[tid] = s;
    __syncthreads();
    for (int off = 128; off > 0; off >>= 1) {
        if (tid < off) sm[tid] += sm[tid + off];
        __syncthreads();
    }
    if (tid == 0) {
        double mse = sm[0] / ((double)N_ROWS * (double)D_DIM);
        loss_out[0] = (float)(1.25 * mse);   // (1 + BETA) * mean((h-q)^2)
    }
}

extern "C" void kernel_launch(void* const* d_in, const int* in_sizes, int n_in,
                              void* d_out, int out_size, void* d_ws, size_t ws_size,
                              hipStream_t stream) {
    const float* x  = (const float*)d_in[0];
    const float* W1 = (const float*)d_in[1];
    const float* b1 = (const float*)d_in[2];
    const float* cb = (const float*)d_in[3];
    const int* qflag = (const int*)d_in[4];

    float* out = (float*)d_out;
    const int NR = in_sizes[0] / D_DIM;        // 262144 rows
    const int nblocks = NR / RPB;              // 4096 tiles

    float* out_h    = out;                                  // [NR*100]
    float* out_pay  = out + (size_t)NR * D_DIM;             // [NR]
    float* out_aux  = out_pay + NR;                         // [NR*100]
    float* out_loss = out_aux + (size_t)NR * D_DIM;         // [1]

    double* partials = (double*)d_ws;                       // 4096 doubles
    const size_t w_off = (size_t)nblocks * sizeof(double);
    unsigned short* Whi = (unsigned short*)((char*)d_ws + w_off);   // 32 KB
    unsigned short* Wlo = Whi + NP * KP;                            // 32 KB

    split_w_kernel<<<(NP * KP) / 256, 256, 0, stream>>>(W1, Whi, Wlo);
    gemm_relu_mfma<<<GRID_GEMM, TPB, 0, stream>>>(x, Whi, Wlo, b1, out_h);
    vq_kernel<<<GRID_GEMM, TPB, 0, stream>>>(out_h, x, W1, b1, cb, qflag,
                                             out_pay, out_aux, partials);
    vq_final_kernel<<<1, 256, 0, stream>>>(partials, nblocks, out_loss);
}

// Round 14
// 119.632 us; speedup vs baseline: 2.8381x; 2.8381x over previous
//
#include <hip/hip_runtime.h>

// Problem constants (B=64, T=4096, D=100, K=4, BETA=0.25)
#define D_DIM   100
#define K_CODES 4
#define RPB     64      // rows per gemm tile
#define TPB     256
#define PITCH   65      // f32 h^T-tile pitch (words)
#define N_ROWS  262144  // B*T
#define KP      128
#define NP      128
#define TAU     0.25    // f64 d2 margin -> exact recompute (R6-proven)
#define GRID_GEMM 1024  // gemm blocks x 4 tiles
#define NTILES  4

typedef __attribute__((ext_vector_type(8))) __bf16 bf16x8;
typedef __attribute__((ext_vector_type(4))) float  f32x4;

__device__ __forceinline__ unsigned short f2bf_rne(float f) {
    unsigned int u = __builtin_bit_cast(unsigned int, f);
    unsigned int r = u + 0x7fffu + ((u >> 16) & 1u);
    return (unsigned short)(r >> 16);
}
__device__ __forceinline__ float bf2f(unsigned short b) {
    unsigned int u = ((unsigned int)b) << 16;
    return __builtin_bit_cast(float, u);
}
__device__ __forceinline__ void load_lds16(const float* g, float* s) {
    __builtin_amdgcn_global_load_lds(
        (const __attribute__((address_space(1))) unsigned int*)g,
        (__attribute__((address_space(3))) unsigned int*)s, 16, 0, 0);
}
__device__ __forceinline__ void stage_x(const float* xg, float* s, int wave, int lane) {
    #pragma unroll
    for (int it = 0; it < 6; ++it) {
        int cbase = it * 256 + wave * 64;
        load_lds16(xg + (size_t)(cbase + lane) * 4, s + cbase * 4);
    }
    if (wave == 0) load_lds16(xg + (size_t)(1536 + lane) * 4, s + 1536 * 4);
}

// raw barrier + LDS-only wait: does NOT drain vmcnt (prefetch stays in flight)
__device__ __forceinline__ void bar_lgkm() {
    __builtin_amdgcn_sched_barrier(0);
    asm volatile("s_waitcnt lgkmcnt(0)" ::: "memory");
    __builtin_amdgcn_s_barrier();
    __builtin_amdgcn_sched_barrier(0);
}
// full drain barrier (staging must have landed)
__device__ __forceinline__ void bar_vm() {
    __builtin_amdgcn_sched_barrier(0);
    asm volatile("s_waitcnt vmcnt(0) lgkmcnt(0)" ::: "memory");
    __builtin_amdgcn_s_barrier();
    __builtin_amdgcn_sched_barrier(0);
}

// ---------------- pre-kernel: split W1 into padded bf16 hi/lo [NP][KP] ----------------
__global__ __launch_bounds__(256) void split_w_kernel(
    const float* __restrict__ W1,
    unsigned short* __restrict__ Whi, unsigned short* __restrict__ Wlo)
{
    int i = blockIdx.x * 256 + threadIdx.x;
    if (i >= NP * KP) return;
    int n = i / KP, k = i % KP;
    float w = (n < D_DIM && k < D_DIM) ? W1[n * D_DIM + k] : 0.0f;
    unsigned short hb = f2bf_rne(w);
    float lo = w - bf2f(hb);
    Whi[i] = hb;
    Wlo[i] = f2bf_rne(lo);
}

// ---------------- Kernel A (v7): gemm v3 + counted-wait pipeline ----------------
// Same numerics as R8-R13. Only the barrier waits changed: interior barriers are
// lgkmcnt-only so the next-tile global_load_lds prefetch is never drained mid-tile.
__global__ __launch_bounds__(TPB, 4) void gemm_relu_mfma(
    const float* __restrict__ x,
    const unsigned short* __restrict__ Whi, const unsigned short* __restrict__ Wlo,
    const float* __restrict__ b1, float* __restrict__ out_h)
{
    __shared__ __align__(16) float buf0[6500];
    __shared__ __align__(16) float buf1[6500];
    const int tid  = threadIdx.x;
    const int lane = tid & 63;
    const int wave = tid >> 6;

    const int bcol0 = wave * 32;
    const int bn  = lane & 15;
    const int bk  = (lane >> 4) * 8;
    bf16x8 bh[2][4], bl[2][4];
    #pragma unroll
    for (int ct = 0; ct < 2; ++ct) {
        int n = bcol0 + ct * 16 + bn;
        #pragma unroll
        for (int kt = 0; kt < 4; ++kt) {
            int off = n * KP + kt * 32 + bk;
            bh[ct][kt] = *reinterpret_cast<const bf16x8*>(Whi + off);
            bl[ct][kt] = *reinterpret_cast<const bf16x8*>(Wlo + off);
        }
    }
    float bias[2];
    #pragma unroll
    for (int ct = 0; ct < 2; ++ct) {
        int n = bcol0 + ct * 16 + bn;
        bias[ct] = (n < D_DIM) ? b1[n] : 0.0f;
    }
    if (tid < 32) { buf0[6400 + tid] = 0.0f; buf1[6400 + tid] = 0.0f; }
    stage_x(x + (size_t)blockIdx.x * RPB * D_DIM, buf0, wave, lane);

    const int am = lane & 15;
    const int ak = (lane >> 4) * 8;

    for (int it = 0; it < NTILES; ++it) {
        const int tile = blockIdx.x + it * GRID_GEMM;
        const int rowBase = tile * RPB;
        float* cur = (it & 1) ? buf1 : buf0;
        float* nxt = (it & 1) ? buf0 : buf1;

        bar_vm();   // cur staged (prefetch had the whole prior tile to fly) + prev writeout LDS-reads done

        if (it + 1 < NTILES)   // prefetch next tile; stays in flight across lgkm barriers
            stage_x(x + (size_t)(blockIdx.x + (it + 1) * GRID_GEMM) * RPB * D_DIM,
                    nxt, wave, lane);

        f32x4 acc[4][2];
        #pragma unroll
        for (int rt = 0; rt < 4; ++rt) {
            acc[rt][0] = (f32x4){0.f, 0.f, 0.f, 0.f};
            acc[rt][1] = (f32x4){0.f, 0.f, 0.f, 0.f};
        }
        #pragma unroll
        for (int rt = 0; rt < 4; ++rt) {
            const int rbase = (rt * 16 + am) * D_DIM;
            #pragma unroll
            for (int kt = 0; kt < 4; ++kt) {
                const float* p = cur + rbase + kt * 32 + ak;
                f32x4 f0 = *reinterpret_cast<const f32x4*>(p);
                f32x4 f1 = *reinterpret_cast<const f32x4*>(p + 4);
                bf16x8 ah, al;
                #pragma unroll
                for (int i = 0; i < 4; ++i) {
                    __bf16 h0 = (__bf16)f0[i];
                    ah[i] = h0;
                    al[i] = (__bf16)(f0[i] - (float)h0);
                    __bf16 h1 = (__bf16)f1[i];
                    ah[4 + i] = h1;
                    al[4 + i] = (__bf16)(f1[i] - (float)h1);
                }
                acc[rt][0] = __builtin_amdgcn_mfma_f32_16x16x32_bf16(ah, bl[0][kt], acc[rt][0], 0, 0, 0);
                acc[rt][0] = __builtin_amdgcn_mfma_f32_16x16x32_bf16(al, bh[0][kt], acc[rt][0], 0, 0, 0);
                acc[rt][0] = __builtin_amdgcn_mfma_f32_16x16x32_bf16(ah, bh[0][kt], acc[rt][0], 0, 0, 0);
                acc[rt][1] = __builtin_amdgcn_mfma_f32_16x16x32_bf16(ah, bl[1][kt], acc[rt][1], 0, 0, 0);
                acc[rt][1] = __builtin_amdgcn_mfma_f32_16x16x32_bf16(al, bh[1][kt], acc[rt][1], 0, 0, 0);
                acc[rt][1] = __builtin_amdgcn_mfma_f32_16x16x32_bf16(ah, bh[1][kt], acc[rt][1], 0, 0, 0);
            }
        }
        bar_lgkm();   // all MFMA ds_reads of cur done; prefetch NOT drained

        #pragma unroll
        for (int rt = 0; rt < 4; ++rt) {
            int rb = rt * 16 + (lane >> 4) * 4;
            #pragma unroll
            for (int ct = 0; ct < 2; ++ct) {
                int n = bcol0 + ct * 16 + bn;
                if (n < D_DIM) {
                    #pragma unroll
                    for (int i = 0; i < 4; ++i)
                        cur[n * PITCH + rb + i] = fmaxf(acc[rt][ct][i] + bias[ct], 0.0f);
                }
            }
        }
        bar_lgkm();   // h^T visible; prefetch still in flight

        float* hg = out_h + (size_t)rowBase * D_DIM;
        for (int v = tid; v < RPB * 25; v += TPB) {
            int r = v / 25;
            int d = (v % 25) * 4;
            reinterpret_cast<float4*>(hg)[v] = make_float4(
                cur[d * PITCH + r], cur[(d + 1) * PITCH + r],
                cur[(d + 2) * PITCH + r], cur[(d + 3) * PITCH + r]);
        }
    }
}

// ---------------- Kernel B: VQ (R9 verbatim: staged, margin-guarded, proven) ----------------
__global__ __launch_bounds__(TPB) void vq_kernel(
    const float* __restrict__ h, const float* __restrict__ x,
    const float* __restrict__ W1, const float* __restrict__ b1,
    const float* __restrict__ cb, const int* __restrict__ qflag,
    float* __restrict__ out_pay, float* __restrict__ out_aux,
    double* __restrict__ partials)
{
    __shared__ float  tile[D_DIM][PITCH];
    __shared__ double d2s[K_CODES][RPB];
    __shared__ int    idxs[RPB];
    __shared__ unsigned long long flagmask;
    const int tid  = threadIdx.x;
    const int lane = tid & 63;
    const int wave = tid >> 6;
    const int blk  = blockIdx.x;
    const int rowBase = blk * RPB;
    const int qz = *qflag;

    if (qz) {
        const float* hgc = h + (size_t)rowBase * D_DIM;
        for (int v = tid; v < (RPB * D_DIM) / 4; v += TPB) {
            float4 val = reinterpret_cast<const float4*>(hgc)[v];
            int r = v / 25;
            int d = (v % 25) * 4;
            tile[d + 0][r] = val.x; tile[d + 1][r] = val.y;
            tile[d + 2][r] = val.z; tile[d + 3][r] = val.w;
        }
        __syncthreads();
        {
            const int k = __builtin_amdgcn_readfirstlane(wave & 3);
            const float* crow = cb + k * D_DIM;
            double s = 0.0;
            #pragma unroll
            for (int d = 0; d < D_DIM; ++d) {
                double dh = (double)tile[d][lane] - (double)crow[d];
                s = fma(dh, dh, s);
            }
            d2s[k][lane] = s;
        }
        __syncthreads();

        if (wave == 0) {
            double best = d2s[0][lane], second = 1e300;
            int bi = 0;
            #pragma unroll
            for (int k = 1; k < K_CODES; ++k) {
                double v = d2s[k][lane];
                if (v < best) { second = best; best = v; bi = k; }
                else if (v < second) { second = v; }
            }
            idxs[lane] = bi;
            unsigned long long m = __ballot((second - best) < TAU);
            if (lane == 0) flagmask = m;
        }
        __syncthreads();

        {
            unsigned long long m = flagmask;
            int i = 0;
            while (m) {
                int r = __ffsll((long long)m) - 1;
                m &= m - 1;
                if ((i & 3) == wave) {
                    const int e1 = lane;
                    const int e2 = 64 + lane;
                    const bool has2 = (e2 < D_DIM);
                    float z1 = b1[e1];
                    float z2 = has2 ? b1[e2] : 0.0f;
                    const float* xr  = x + (size_t)(rowBase + r) * D_DIM;
                    const float* w1r = W1 + e1 * D_DIM;
                    const float* w2r = W1 + (has2 ? e2 : 0) * D_DIM;
                    #pragma unroll
                    for (int d4 = 0; d4 < 25; ++d4) {
                        float4 xv = reinterpret_cast<const float4*>(xr)[d4];
                        float4 wa = reinterpret_cast<const float4*>(w1r)[d4];
                        z1 = fmaf(xv.x, wa.x, z1); z1 = fmaf(xv.y, wa.y, z1);
                        z1 = fmaf(xv.z, wa.z, z1); z1 = fmaf(xv.w, wa.w, z1);
                        float4 wb = reinterpret_cast<const float4*>(w2r)[d4];
                        z2 = fmaf(xv.x, wb.x, z2); z2 = fmaf(xv.y, wb.y, z2);
                        z2 = fmaf(xv.z, wb.z, z2); z2 = fmaf(xv.w, wb.w, z2);
                    }
                    float h1 = fmaxf(z1, 0.0f);
                    float h2 = fmaxf(z2, 0.0f);
                    double dk[K_CODES];
                    #pragma unroll
                    for (int k = 0; k < K_CODES; ++k) {
                        double p;
                        {
                            double dh = (double)h1 - (double)cb[k * D_DIM + e1];
                            p = dh * dh;
                        }
                        if (has2) {
                            double dh = (double)h2 - (double)cb[k * D_DIM + e2];
                            p = fma(dh, dh, p);
                        }
                        for (int off = 32; off > 0; off >>= 1)
                            p += __shfl_down(p, off);
                        dk[k] = p;
                    }
                    if (lane == 0) {
                        double best = dk[0];
                        int bi = 0;
                        #pragma unroll
                        for (int k = 1; k < K_CODES; ++k)
                            if (dk[k] < best) { best = dk[k]; bi = k; }
                        idxs[r] = bi;
                    }
                }
                ++i;
            }
        }
        __syncthreads();

        if (wave == 0) {
            int bi = idxs[lane];
            out_pay[rowBase + lane] = (float)bi;
            double d2min = d2s[bi][lane];
            for (int off = 32; off > 0; off >>= 1)
                d2min += __shfl_down(d2min, off);
            if (lane == 0) partials[blk] = d2min;
        }

        float* ag = out_aux + (size_t)rowBase * D_DIM;
        for (int v = tid; v < (RPB * D_DIM) / 4; v += TPB) {
            int r = v / 25;
            int d = (v % 25) * 4;
            int bi = idxs[r];
            reinterpret_cast<float4*>(ag)[v] =
                reinterpret_cast<const float4*>(cb + bi * D_DIM + d)[0];
        }
    } else {
        if (wave == 0) {
            out_pay[rowBase + lane] = 0.0f;
            if (lane == 0) partials[blk] = 0.0;
        }
        float* ag = out_aux + (size_t)rowBase * D_DIM;
        for (int v = tid; v < (RPB * D_DIM) / 4; v += TPB)
            reinterpret_cast<float4*>(ag)[v] = make_float4(0, 0, 0, 0);
    }
}

// ---------------- deterministic final loss reduce ----------------
__global__ __launch_bounds__(256) void vq_final_kernel(
    const double* __restrict__ partials, int n, float* __restrict__ loss_out)
{
    __shared__ double sm[256];
    int tid = threadIdx.x;
    double s = 0.0;
    for (int i = tid; i < n; i += 256) s += partials[i];
    sm[tid] = s;
    __syncthreads();
    for (int off = 128; off > 0; off >>= 1) {
        if (tid < off) sm[tid] += sm[tid + off];
        __syncthreads();
    }
    if (tid == 0) {
        double mse = sm[0] / ((double)N_ROWS * (double)D_DIM);
        loss_out[0] = (float)(1.25 * mse);   // (1 + BETA) * mean((h-q)^2)
    }
}

extern "C" void kernel_launch(void* const* d_in, const int* in_sizes, int n_in,
                              void* d_out, int out_size, void* d_ws, size_t ws_size,
                              hipStream_t stream) {
    const float* x  = (const float*)d_in[0];
    const float* W1 = (const float*)d_in[1];
    const float* b1 = (const float*)d_in[2];
    const float* cb = (const float*)d_in[3];
    const int* qflag = (const int*)d_in[4];

    float* out = (float*)d_out;
    const int NR = in_sizes[0] / D_DIM;        // 262144 rows
    const int nblocks = NR / RPB;              // 4096 tiles

    float* out_h    = out;                                  // [NR*100]
    float* out_pay  = out + (size_t)NR * D_DIM;             // [NR]
    float* out_aux  = out_pay + NR;                         // [NR*100]
    float* out_loss = out_aux + (size_t)NR * D_DIM;         // [1]

    double* partials = (double*)d_ws;                       // 32 KB
    const size_t w_off = (size_t)nblocks * sizeof(double);
    unsigned short* Whi = (unsigned short*)((char*)d_ws + w_off);   // 32 KB
    unsigned short* Wlo = Whi + NP * KP;                            // 32 KB

    split_w_kernel<<<(NP * KP) / 256, 256, 0, stream>>>(W1, Whi, Wlo);
    gemm_relu_mfma<<<GRID_GEMM, TPB, 0, stream>>>(x, Whi, Wlo, b1, out_h);
    vq_kernel<<<nblocks, TPB, 0, stream>>>(out_h, x, W1, b1, cb, qflag,
                                           out_pay, out_aux, partials);
    vq_final_kernel<<<1, 256, 0, stream>>>(partials, nblocks, out_loss);
}